// Round 13
// baseline (37.721 us; speedup 1.0000x reference)
//
#include <hip/hip_runtime.h>

// x: [2,2,8,64,64,64] fp32 0/1 -> 2048 images of 64x64.
// Per image: #4-connected components; per group of 64 images: sum // 64 -> float.
//
// R6 structure (best measured: 21.3us): one 256-thread block per image,
// thread = 4*row + quarter, 16 px/thread loads, width-4 shuffle butterfly row
// masks, union-find over runs (id = row*32+rank) in 8 KB LDS with atomicMin
// hooking, components = runs - root_kills.
// R13 change: finalize kernel FUSED via packed global atomicAdd
// (sum in bits 0..19, contributor count in bits 20+). The unique 64th
// contributor block writes out[g] = sum >> 6. Replaces a dependent 1-block
// dispatch (~2-4us serial tail) with a 128 B memset node.
// Union-phase restructurings (R7/R8/R11/R12) all regressed or were neutral —
// R6's union is kept verbatim.
constexpr int NPIX = 64 * 64;
constexpr int PATCHES = 64;
constexpr int RPR = 32;          // run slots per row
constexpr int TABLE = 64 * RPR;  // 2048

// Find with path halving (benign race: only ever points i to an ancestor).
__device__ __forceinline__ int find_root(volatile int* p, int i) {
    while (true) {
        int pi = p[i];
        if (pi == i) return i;
        int gp = p[pi];
        if (gp == pi) return pi;
        p[i] = gp;
        i = gp;
    }
}

// Priority union via atomicMin hooking. Returns 1 iff this call killed a
// root (p[b] transitions b -> smaller exactly once, seen by a unique thread).
__device__ __forceinline__ int merge(int* p, int a, int b) {
    while (true) {
        a = find_root(p, a);
        b = find_root(p, b);
        if (a == b) return 0;
        if (a > b) { int t = a; a = b; b = t; }  // a < b
        int old = atomicMin(&p[b], a);
        if (old == b) return 1;  // we killed root b
        b = old;                 // p[b] was already smaller; chase it
    }
}

__global__ __launch_bounds__(256, 8) void cc_kernel(const float* __restrict__ in,
                                                    unsigned* __restrict__ gsum,
                                                    float* __restrict__ out) {
    __shared__ int par[TABLE];               // 8 KB
    __shared__ unsigned long long mrow[64];  // row masks
    __shared__ int wpart[4];
    const int tid = threadIdx.x;
    const int img = blockIdx.x;
    const int r = tid >> 2;  // row 0..63
    const int q = tid & 3;   // quarter 0..3

    // ---- load 16 consecutive pixels (4 x float4 = one 64B line) ----
    const float4* src =
        reinterpret_cast<const float4*>(in + (size_t)img * NPIX + r * 64 + q * 16);
    float4 buf[4];
#pragma unroll
    for (int k = 0; k < 4; ++k) buf[k] = src[k];

    // ---- identity-init run table while loads are in flight ----
    {
        int b0 = tid * 4;
        *reinterpret_cast<int4*>(&par[b0]) = make_int4(b0, b0 + 1, b0 + 2, b0 + 3);
        int b1 = 1024 + tid * 4;
        *reinterpret_cast<int4*>(&par[b1]) = make_int4(b1, b1 + 1, b1 + 2, b1 + 3);
    }

    // ---- 16-bit quarter mask, then full row mask via width-4 butterfly ----
    unsigned qm = 0;
#pragma unroll
    for (int k = 0; k < 4; ++k) {
        qm |= (buf[k].x > 0.5f ? 1u : 0u) << (4 * k);
        qm |= (buf[k].y > 0.5f ? 2u : 0u) << (4 * k);
        qm |= (buf[k].z > 0.5f ? 4u : 0u) << (4 * k);
        qm |= (buf[k].w > 0.5f ? 8u : 0u) << (4 * k);
    }
    unsigned long long m = (unsigned long long)qm << (16 * q);
    m |= __shfl_xor(m, 1, 4);
    m |= __shfl_xor(m, 2, 4);  // all 4 threads of row r hold the full mask

    if (q == 0) mrow[r] = m;
    __syncthreads();  // par + mrow visible

    const unsigned long long ma = m;
    const unsigned long long mb = (r < 63) ? mrow[r + 1] : 0ull;
    const unsigned long long sa = ma & ~(ma << 1);
    const unsigned long long sb = mb & ~(mb << 1);
    const unsigned long long qmask = 0xFFFFull << (16 * q);

    int cnt = __popcll(sa & qmask);  // run starts partitioned by quarter

    // ---- unions: overlap segments whose start bit is in this quarter ----
    unsigned long long both = ma & mb;
    unsigned long long ov = (both & ~(both << 1)) & qmask;
    while (ov) {
        int x = __builtin_ctzll(ov);
        ov &= ov - 1;
        unsigned long long below = (2ull << x) - 1;  // bits 0..x
        int ida = r * RPR + __popcll(sa & below) - 1;
        int idb = (r + 1) * RPR + __popcll(sb & below) - 1;
        cnt -= merge(par, ida, idb);
    }

    // ---- block reduction of (runs - kills) ----
#pragma unroll
    for (int d = 32; d > 0; d >>= 1) cnt += __shfl_xor(cnt, d, 64);
    if ((tid & 63) == 0) wpart[tid >> 6] = cnt;
    __syncthreads();

    // ---- fused group accumulate: sum in bits 0..19, arrivals in bits 20+ ----
    if (tid == 0) {
        unsigned total = (unsigned)(wpart[0] + wpart[1] + wpart[2] + wpart[3]);
        const int g = img / PATCHES;
        unsigned old = atomicAdd(&gsum[g], total + (1u << 20));
        if ((old >> 20) == PATCHES - 1) {  // unique last contributor
            unsigned s = (old & 0xFFFFFu) + total;
            out[g] = (float)(s >> 6);  // sum // 64
        }
    }
}

extern "C" void kernel_launch(void* const* d_in, const int* in_sizes, int n_in,
                              void* d_out, int out_size, void* d_ws, size_t ws_size,
                              hipStream_t stream) {
    const float* x = (const float*)d_in[0];
    float* out = (float*)d_out;
    unsigned* gsum = (unsigned*)d_ws;

    const int nimg = in_sizes[0] / NPIX;  // 2048
    const int ngroups = out_size;         // 32

    hipMemsetAsync(gsum, 0, ngroups * sizeof(unsigned), stream);
    cc_kernel<<<nimg, 256, 0, stream>>>(x, gsum, out);
}